// Round 9
// baseline (109.002 us; speedup 1.0000x reference)
//
#include <hip/hip_runtime.h>

typedef _Float16 f16;
typedef f16 f16x2 __attribute__((ext_vector_type(2)));
typedef f16 f16x4 __attribute__((ext_vector_type(4)));
typedef f16 f16x8 __attribute__((ext_vector_type(8)));
typedef float f32x4 __attribute__((ext_vector_type(4)));

constexpr int Mdim = 32768, Ndim = 1024, Kdim = 1024;
constexpr int BM = 256, BN = 256, BK = 64;
constexpr int NT = Kdim / BK;   // 16 K-steps

static __device__ inline f16x2 cvt2(float a, float b) {
    return __builtin_bit_cast(f16x2, __builtin_amdgcn_cvt_pkrtz(a, b));
}
static __device__ inline f16x4 cvt4(float4 v) {
    f16x2 lo = cvt2(v.x, v.y), hi = cvt2(v.z, v.w);
    return __builtin_shufflevector(lo, hi, 0, 1, 2, 3);
}
static __device__ inline void bar() {          // raw: no vmcnt drain
    asm volatile("" ::: "memory");
    __builtin_amdgcn_s_barrier();
    asm volatile("" ::: "memory");
}
static __device__ inline void lgkm0() {
    asm volatile("s_waitcnt lgkmcnt(0)" ::: "memory");
}

// out[b,n] = fp32(sum_k fp16(x[b,k]) * fp16(w[n,k])) + bias[n]
// (reference's early-termination mask is always-true: tstat >= 0 > TAU never holds)
//
// R8 structure with the s=1 fragment-address fix: swizzle mask (lane&7)<<4
// occupies bits 4-6; the s*64 term is bit 6 and must be XORed INSIDE the
// swizzle. Since base bit6==0: (Y+64)^m == (Y^m)^64, so use ^64, never +64
// (which carries into bit 7 for lanes with lane&4).
__global__ __launch_bounds__(512, 2)
void etrow_gemm(const float* __restrict__ X, const float* __restrict__ W,
                const float* __restrict__ bias, float* __restrict__ out)
{
    __shared__ f16 As[2][BM * BK];   // 32 KB per buffer (buf1 at byte 32768)
    __shared__ f16 Bs[2][BN * BK];

    // bijective XCD-aware swizzle (512 blocks, 64 per XCD)
    const int bid = blockIdx.x;
    const int cpx = gridDim.x >> 3;
    const int wg  = (bid & 7) * cpx + (bid >> 3);
    const int mIdx = wg >> 2;        // 4 n-tiles, n fastest
    const int nIdx = wg & 3;

    const int tid  = threadIdx.x;
    const int lane = tid & 63;
    const int wave = tid >> 6;            // 0..7
    const int wr   = (wave >> 2) * 128;   // 2m x 4n waves, wave tile 128x64
    const int wc   = (wave & 3) * 64;

    const int r0 = tid >> 4;    // 0..31 staging row
    const int c4 = tid & 15;    // float4 slot within 64-float K slab

    // persistent addresses: everything else is compile-time immediates
    const float* xthr = X + (size_t)mIdx * BM * Kdim + r0 * Kdim + c4 * 4;
    const float* wthr = W + (size_t)nIdx * BN * Kdim + r0 * Kdim + c4 * 4;
    const int wbyte = (r0 * 128 + c4 * 8) ^ ((r0 & 7) << 4);  // + q*4096 + buf
    // fragment base (s=0): r = wr|wc + quad*16 + (lane&15); (r&7)==(lane&7)
    const int abyte = ((wr + (lane & 15)) * 128 + (lane >> 4) * 16) ^ ((lane & 7) << 4);
    const int bbyte = ((wc + (lane & 15)) * 128 + (lane >> 4) * 16) ^ ((lane & 7) << 4);
    char* const Ab = (char*)&As[0][0];
    char* const Bb = (char*)&Bs[0][0];

    float4 SA[8], SB[8];        // one in-flight set per leg (spill tripwire:
    f32x4 acc[8][4] = {};       // WRITE_SIZE > 140 MB)

    auto issueA = [&](int kt) {
        const float* p = xthr + kt * BK;
        #pragma unroll
        for (int q = 0; q < 8; ++q)
            SA[q] = *(const float4*)(p + q * 32 * Kdim);
    };
    auto issueB = [&](int kt) {
        const float* p = wthr + kt * BK;
        #pragma unroll
        for (int q = 0; q < 8; ++q)
            SB[q] = *(const float4*)(p + q * 32 * Kdim);
    };
    auto cvtWrA = [&](int bufoff) {
        #pragma unroll
        for (int q = 0; q < 8; ++q)
            *(f16x4*)(Ab + bufoff + wbyte + q * 4096) = cvt4(SA[q]);
    };
    auto cvtWrB = [&](int bufoff) {
        #pragma unroll
        for (int q = 0; q < 8; ++q)
            *(f16x4*)(Bb + bufoff + wbyte + q * 4096) = cvt4(SB[q]);
    };

    auto phase = [&](int co, int p) {   // p = m-quadrant pair (0 or 1)
        f16x8 af[4], bf[4];
        #pragma unroll
        for (int mi = 0; mi < 4; ++mi)
            af[mi] = *(const f16x8*)(Ab + co + ((abyte + (p * 4 + mi) * 2048)));
        #pragma unroll
        for (int j = 0; j < 4; ++j)
            bf[j] = *(const f16x8*)(Bb + co + ((bbyte + j * 2048)));
        bar();
        lgkm0();
        __builtin_amdgcn_s_setprio(1);
        #pragma unroll
        for (int mi = 0; mi < 4; ++mi)
            #pragma unroll
            for (int j = 0; j < 4; ++j)
                acc[p * 4 + mi][j] = __builtin_amdgcn_mfma_f32_16x16x32_f16(
                    af[mi], bf[j], acc[p * 4 + mi][j], 0, 0, 0);
        // s=1 frags: bit 6 toggles INSIDE the swizzle -> XOR, not add
        #pragma unroll
        for (int mi = 0; mi < 4; ++mi)
            af[mi] = *(const f16x8*)(Ab + co + ((abyte + (p * 4 + mi) * 2048) ^ 64));
        #pragma unroll
        for (int j = 0; j < 4; ++j)
            bf[j] = *(const f16x8*)(Bb + co + ((bbyte + j * 2048) ^ 64));
        #pragma unroll
        for (int mi = 0; mi < 4; ++mi)
            #pragma unroll
            for (int j = 0; j < 4; ++j)
                acc[p * 4 + mi][j] = __builtin_amdgcn_mfma_f32_16x16x32_f16(
                    af[mi], bf[j], acc[p * 4 + mi][j], 0, 0, 0);
        __builtin_amdgcn_s_setprio(0);
        bar();
    };

    // prologue: tile0 staged; tile1 loads in flight
    issueA(0); cvtWrA(0);
    issueB(0); cvtWrB(0);
    issueA(1); issueB(1);
    lgkm0();
    bar();

    for (int t = 0; t < NT; ++t) {
        const int co = (t & 1) << 15;      // cur buffer byte offset
        const int no = co ^ 32768;
        const bool h1 = t + 1 < NT, h2 = t + 2 < NT;

        // phase 0: publish A(t+1) (loads a full step old -> free vmcnt),
        // launch A(t+2) (WAR on SA; stays in flight across barriers), rows 0-63
        if (h1) cvtWrA(no);
        if (h2) issueA(t + 2);
        phase(co, 0);
        // phase 1: publish B(t+1), launch B(t+2), rows 64-127
        if (h1) cvtWrB(no);
        if (h2) issueB(t + 2);
        phase(co, 1);
    }

    // epilogue: C/D layout col = lane&15, row = (lane>>4)*4 + reg (m89-verified)
    const int col0  = nIdx * BN + wc + (lane & 15);
    const int rbase = mIdx * BM + wr + (lane >> 4) * 4;
    float bv[4];
    #pragma unroll
    for (int n = 0; n < 4; ++n) bv[n] = bias[col0 + n * 16];

    #pragma unroll
    for (int m = 0; m < 8; ++m) {
        #pragma unroll
        for (int j = 0; j < 4; ++j) {
            const int row = rbase + m * 16 + j;
            float* o = out + (size_t)row * Ndim + col0;
            #pragma unroll
            for (int n = 0; n < 4; ++n)
                o[n * 16] = acc[m][n][j] + bv[n];
        }
    }
}

extern "C" void kernel_launch(void* const* d_in, const int* in_sizes, int n_in,
                              void* d_out, int out_size, void* d_ws, size_t ws_size,
                              hipStream_t stream) {
    const float* X  = (const float*)d_in[0];
    const float* W  = (const float*)d_in[1];
    const float* bs = (const float*)d_in[2];
    float* out = (float*)d_out;
    const int grid = (Mdim / BM) * (Ndim / BN);   // 512 blocks
    etrow_gemm<<<grid, 512, 0, stream>>>(X, W, bs, out);
}